// Round 13
// baseline (563.708 us; speedup 1.0000x reference)
//
#include <hip/hip_runtime.h>
#include <math.h>

#define T_  6
#define NN  4096
#define XD_ 64
#define H_  256
#define ZZ  128
#define EE  131072

typedef unsigned short u16;
typedef __attribute__((ext_vector_type(8))) short short8;
typedef __attribute__((ext_vector_type(8))) unsigned short u16x8;
typedef __attribute__((ext_vector_type(4))) float f32x4;

__device__ __forceinline__ float bf2f(u16 u) { return __uint_as_float(((unsigned)u) << 16); }
__device__ __forceinline__ u16 f2bf(float f) {
    unsigned x = __float_as_uint(f);
    return (u16)((x + 0x7FFFu + ((x >> 16) & 1u)) >> 16);   // RTNE
}

// ---------------------------------------------------- degree hist (batched t)
__global__ void k_deg(const int* __restrict__ edges, int* __restrict__ degcnt) {
    int t = blockIdx.y;
    int e = blockIdx.x * 256 + threadIdx.x;
    const int* rows = edges + (size_t)t * 2 * EE;
    atomicAdd(&degcnt[t * NN + rows[e]], 1);
}

// ---------------------------------- scan (CSR offsets) + dinv; one block per t
__global__ void k_scan_dinv(const int* __restrict__ degcnt_all,
                            int* __restrict__ row_start_all,
                            int* __restrict__ cursor_all,
                            float* __restrict__ dinv_all) {
    __shared__ int sbuf[1024];
    int tt = blockIdx.x;
    const int* degcnt = degcnt_all + tt * NN;
    int* row_start = row_start_all + tt * (NN + 1);
    int* cursor = cursor_all + tt * NN;
    float* dinv = dinv_all + tt * NN;
    int t = threadIdx.x;
    int b = t * 4;
    int v0 = degcnt[b + 0], v1 = degcnt[b + 1], v2 = degcnt[b + 2], v3 = degcnt[b + 3];
    dinv[b + 0] = rsqrtf((float)(v0 + 1));   // +1: self loop
    dinv[b + 1] = rsqrtf((float)(v1 + 1));
    dinv[b + 2] = rsqrtf((float)(v2 + 1));
    dinv[b + 3] = rsqrtf((float)(v3 + 1));
    int s = v0 + v1 + v2 + v3;
    sbuf[t] = s;
    __syncthreads();
    for (int off = 1; off < 1024; off <<= 1) {
        int x = sbuf[t];
        int y = (t >= off) ? sbuf[t - off] : 0;
        __syncthreads();
        sbuf[t] = x + y;
        __syncthreads();
    }
    int excl = sbuf[t] - s;
    int r0 = excl, r1 = excl + v0, r2 = r1 + v1, r3 = r2 + v2;
    row_start[b + 0] = r0; cursor[b + 0] = r0;
    row_start[b + 1] = r1; cursor[b + 1] = r1;
    row_start[b + 2] = r2; cursor[b + 2] = r2;
    row_start[b + 3] = r3; cursor[b + 3] = r3;
    if (t == 1023) row_start[NN] = r3 + v3;
}

// --------------------- CSR scatter (1D, batched t) + t=0 prior_mu broadcast
// writes packed (col, val-bits) int2 per edge
__global__ void k_scatter(const int* __restrict__ edges,
                          int* __restrict__ cursor, const float* __restrict__ dinv,
                          int2* __restrict__ cv,
                          const float* __restrict__ pm0, float* __restrict__ out_pm) {
    int idx = blockIdx.x * 256 + threadIdx.x;
    if (idx < T_ * EE) {
        int t = idx >> 17, e = idx & (EE - 1);
        const int* rows = edges + (size_t)t * 2 * EE;
        const int* cols = rows + EE;
        int r = rows[e], cc = cols[e];
        int pos = atomicAdd(&cursor[t * NN + r], 1);
        float v = dinv[t * NN + r] * dinv[t * NN + cc];
        cv[(size_t)t * EE + pos] = make_int2(cc, __float_as_int(v));
        return;
    }
    idx -= T_ * EE;
    if (idx < NN * ZZ / 4) {                 // broadcast pm0 to out prior_mu t=0
        int j4 = idx & 31;
        ((float4*)out_pm)[idx] = *(const float4*)(pm0 + j4 * 4);
    }
}

// ------------------------------------------------- SpMM row (one wave, bf16)
// Direct broadcast loads of packed (col,val): all 32 lanes of a half-wave read
// the same int2 (hardware broadcast) -> no ds_bpermute on the critical path.
// 8 edges/iter (4 per half, 4 gathers in flight). Per-half accumulation order
// identical to prior versions (ascending even/odd edges).
__device__ __forceinline__ void sp_row_wave(const u16* __restrict__ Y,
                                            const int* __restrict__ row_start,
                                            const int2* __restrict__ cv,
                                            const float* __restrict__ dinv,
                                            u16* __restrict__ outp, int ldo, int r) {
    int lane = threadIdx.x & 63;
    int half = lane >> 5;
    int cg2 = lane & 31;
    int s0 = row_start[r], s1 = row_start[r + 1];
    float a[8] = {0.f, 0.f, 0.f, 0.f, 0.f, 0.f, 0.f, 0.f};
    for (int e = s0; e < s1; e += 8) {
        int e0 = e + half, e1 = e + 2 + half, e2 = e + 4 + half, e3 = e + 6 + half;
        int lim = s1 - 1;
        int2 c0 = cv[min(e0, lim)];
        int2 c1 = cv[min(e1, lim)];
        int2 c2 = cv[min(e2, lim)];
        int2 c3 = cv[min(e3, lim)];
        u16x8 y0 = *(const u16x8*)(Y + (size_t)c0.x * H_ + cg2 * 8);
        u16x8 y1 = *(const u16x8*)(Y + (size_t)c1.x * H_ + cg2 * 8);
        u16x8 y2 = *(const u16x8*)(Y + (size_t)c2.x * H_ + cg2 * 8);
        u16x8 y3 = *(const u16x8*)(Y + (size_t)c3.x * H_ + cg2 * 8);
        float v0 = (e0 < s1) ? __int_as_float(c0.y) : 0.f;
        float v1 = (e1 < s1) ? __int_as_float(c1.y) : 0.f;
        float v2 = (e2 < s1) ? __int_as_float(c2.y) : 0.f;
        float v3 = (e3 < s1) ? __int_as_float(c3.y) : 0.f;
#pragma unroll
        for (int j = 0; j < 8; ++j) a[j] += v0 * bf2f(y0[j]);
#pragma unroll
        for (int j = 0; j < 8; ++j) a[j] += v1 * bf2f(y1[j]);
#pragma unroll
        for (int j = 0; j < 8; ++j) a[j] += v2 * bf2f(y2[j]);
#pragma unroll
        for (int j = 0; j < 8; ++j) a[j] += v3 * bf2f(y3[j]);
    }
#pragma unroll
    for (int j = 0; j < 8; ++j) a[j] += __shfl_xor(a[j], 32);
    if (half == 0) {
        float dr = dinv[r], sc = dr * dr;
        u16x8 ys = *(const u16x8*)(Y + (size_t)r * H_ + cg2 * 8);
        u16x8 o;
#pragma unroll
        for (int j = 0; j < 8; ++j) o[j] = f2bf(a[j] + sc * bf2f(ys[j]));
        *(u16x8*)(outp + (size_t)r * ldo + cg2 * 8) = o;
    }
}

// batched-t SpMM: 4 rows per block (1 wave each), grid (NN/4, nt)
__global__ void k_spmm(const u16* __restrict__ Y1,
                       const int* __restrict__ row_start_all, const int2* __restrict__ cv_all,
                       const float* __restrict__ dinv_all,
                       u16* __restrict__ out1, int ldo,
                       long long sY, long long sO) {
    int t = blockIdx.y;
    int w = threadIdx.x >> 6;
    sp_row_wave(Y1 + (size_t)t * sY, row_start_all + (size_t)t * (NN + 1),
                cv_all + (size_t)t * EE,
                dinv_all + (size_t)t * NN, out1 + (size_t)t * sO, ldo,
                blockIdx.x * 4 + w);
}

// ------------------------------------------------------------ MFMA GEMM core
// A row-major bf16, BT = B^T [N][K] bf16; accumulates TILE x TILE at (row0,col0).
// LDS XOR-swizzled (byte ^= (row&7)<<4); staged via global_load_lds with
// pre-swizzled per-lane global source.
template<int MF>
__device__ __forceinline__ void mm_core(const u16* __restrict__ A, int lda,
                                        const u16* __restrict__ BT, int ldbt, int K,
                                        int row0, int col0,
                                        f32x4 acc[MF][MF], char* smem) {
    constexpr int TILE = MF * 32;
    u16* As = (u16*)smem;
    u16* Bs = As + TILE * 64;
    const int lane = threadIdx.x & 63;
    const int w = threadIdx.x >> 6;
    const int wr = (w >> 1) * (TILE / 2);
    const int wc = (w & 1) * (TILE / 2);

    int gRow[MF], gCol[MF];
#pragma unroll
    for (int i = 0; i < MF; ++i) {
        int G = (w * MF + i) * 64 + lane;
        int r = G >> 3;
        gRow[i] = r;
        gCol[i] = ((G & 7) ^ (r & 7)) << 3;
    }

    for (int k0 = 0; k0 < K; k0 += 64) {
#pragma unroll
        for (int i = 0; i < MF; ++i) {
            const u16* sa = A + (size_t)(row0 + gRow[i]) * lda + k0 + gCol[i];
            __builtin_amdgcn_global_load_lds(
                (const __attribute__((address_space(1))) void*)sa,
                (__attribute__((address_space(3))) void*)(As + (w * MF + i) * 512), 16, 0, 0);
            const u16* sb = BT + (size_t)(col0 + gRow[i]) * ldbt + k0 + gCol[i];
            __builtin_amdgcn_global_load_lds(
                (const __attribute__((address_space(1))) void*)sb,
                (__attribute__((address_space(3))) void*)(Bs + (w * MF + i) * 512), 16, 0, 0);
        }
        __syncthreads();
#pragma unroll
        for (int kk = 0; kk < 2; ++kk) {
            short8 a[MF], b[MF];
#pragma unroll
            for (int mf = 0; mf < MF; ++mf) {
                int r = wr + mf * 16 + (lane & 15);
                int off = (r * 128 + kk * 64 + (lane >> 4) * 16) ^ ((r & 7) << 4);
                a[mf] = *(const short8*)((const char*)As + off);
            }
#pragma unroll
            for (int nf = 0; nf < MF; ++nf) {
                int r = wc + nf * 16 + (lane & 15);
                int off = (r * 128 + kk * 64 + (lane >> 4) * 16) ^ ((r & 7) << 4);
                b[nf] = *(const short8*)((const char*)Bs + off);
            }
#pragma unroll
            for (int mf = 0; mf < MF; ++mf)
#pragma unroll
                for (int nf = 0; nf < MF; ++nf)
                    acc[mf][nf] = __builtin_amdgcn_mfma_f32_16x16x32_bf16(
                        a[mf], b[nf], acc[mf][nf], 0, 0, 0);
        }
        __syncthreads();
    }
}

// --------------------------------------------- rect 32x64 tile core (acc[2])
// 4 waves: 2 row-halves (16) x 2 col-halves (32). LDS 12KB.
__device__ __forceinline__ void mm_core32(const u16* __restrict__ A, int lda,
                                          const u16* __restrict__ BT, int ldbt, int K,
                                          int row0, int col0,
                                          f32x4 acc[2], char* smem) {
    u16* As = (u16*)smem;            // 32x64 = 4KB
    u16* Bs = As + 32 * 64;          // 64x64 = 8KB
    const int lane = threadIdx.x & 63;
    const int w = threadIdx.x >> 6;
    const int wr = (w >> 1) * 16;
    const int wc = (w & 1) * 32;

    int aR, aC;
    { int G = w * 64 + lane; int r = G >> 3; aR = r; aC = ((G & 7) ^ (r & 7)) << 3; }
    int bR[2], bC[2];
#pragma unroll
    for (int i = 0; i < 2; ++i) {
        int G = (w * 2 + i) * 64 + lane; int r = G >> 3;
        bR[i] = r; bC[i] = ((G & 7) ^ (r & 7)) << 3;
    }

    for (int k0 = 0; k0 < K; k0 += 64) {
        const u16* sa = A + (size_t)(row0 + aR) * lda + k0 + aC;
        __builtin_amdgcn_global_load_lds(
            (const __attribute__((address_space(1))) void*)sa,
            (__attribute__((address_space(3))) void*)(As + w * 512), 16, 0, 0);
#pragma unroll
        for (int i = 0; i < 2; ++i) {
            const u16* sb = BT + (size_t)(col0 + bR[i]) * ldbt + k0 + bC[i];
            __builtin_amdgcn_global_load_lds(
                (const __attribute__((address_space(1))) void*)sb,
                (__attribute__((address_space(3))) void*)(Bs + (w * 2 + i) * 512), 16, 0, 0);
        }
        __syncthreads();
#pragma unroll
        for (int kk = 0; kk < 2; ++kk) {
            short8 a, b[2];
            {
                int r = wr + (lane & 15);
                int off = (r * 128 + kk * 64 + (lane >> 4) * 16) ^ ((r & 7) << 4);
                a = *(const short8*)((const char*)As + off);
            }
#pragma unroll
            for (int nf = 0; nf < 2; ++nf) {
                int r = wc + nf * 16 + (lane & 15);
                int off = (r * 128 + kk * 64 + (lane >> 4) * 16) ^ ((r & 7) << 4);
                b[nf] = *(const short8*)((const char*)Bs + off);
            }
            acc[0] = __builtin_amdgcn_mfma_f32_16x16x32_bf16(a, b[0], acc[0], 0, 0, 0);
            acc[1] = __builtin_amdgcn_mfma_f32_16x16x32_bf16(a, b[1], acc[1], 0, 0, 0);
        }
        __syncthreads();
    }
}

__device__ __forceinline__ void zacc2(f32x4 acc[2][2]) {
#pragma unroll
    for (int i = 0; i < 2; ++i)
#pragma unroll
        for (int j = 0; j < 2; ++j) acc[i][j] = f32x4{0.f, 0.f, 0.f, 0.f};
}

__device__ __forceinline__ void epi_bf16relu(f32x4 acc[2][2], u16* __restrict__ C,
                                             int ldc, int row0, int col0,
                                             const float* __restrict__ bias) {
    const int lane = threadIdx.x & 63, w = threadIdx.x >> 6;
    const int wr = (w >> 1) * 32, wc = (w & 1) * 32;
    const int ci = lane & 15, ri = (lane >> 4) * 4;
#pragma unroll
    for (int mf = 0; mf < 2; ++mf)
#pragma unroll
        for (int nf = 0; nf < 2; ++nf) {
            int row = row0 + wr + mf * 16 + ri;
            int col = col0 + wc + nf * 16 + ci;
            float bv = bias ? bias[col] : 0.f;
#pragma unroll
            for (int i = 0; i < 4; ++i)
                C[(size_t)(row + i) * ldc + col] = f2bf(fmaxf(acc[mf][nf][i] + bv, 0.f));
        }
}

__device__ __forceinline__ void epi32_bf16relu(f32x4 acc[2], u16* __restrict__ C,
                                               int ldc, int row0, int col0,
                                               const float* __restrict__ bias) {
    const int lane = threadIdx.x & 63, w = threadIdx.x >> 6;
    const int wr = (w >> 1) * 16, wc = (w & 1) * 32;
    const int ci = lane & 15, ri = (lane >> 4) * 4;
#pragma unroll
    for (int nf = 0; nf < 2; ++nf) {
        int row = row0 + wr + ri;
        int col = col0 + wc + nf * 16 + ci;
        float bv = bias ? bias[col] : 0.f;
#pragma unroll
        for (int i = 0; i < 4; ++i)
            C[(size_t)(row + i) * ldc + col] = f2bf(fmaxf(acc[nf][i] + bv, 0.f));
    }
}

__device__ __forceinline__ void epi_f32b(f32x4 acc[2][2], float* __restrict__ C,
                                         int ldc, int row0, int col0,
                                         const float* __restrict__ bias) {
    const int lane = threadIdx.x & 63, w = threadIdx.x >> 6;
    const int wr = (w >> 1) * 32, wc = (w & 1) * 32;
    const int ci = lane & 15, ri = (lane >> 4) * 4;
#pragma unroll
    for (int mf = 0; mf < 2; ++mf)
#pragma unroll
        for (int nf = 0; nf < 2; ++nf) {
            int row = row0 + wr + mf * 16 + ri;
            int col = col0 + wc + nf * 16 + ci;
            float bv = bias[col];
#pragma unroll
            for (int i = 0; i < 4; ++i)
                C[(size_t)(row + i) * ldc + col] = acc[mf][nf][i] + bv;
        }
}

// ------------------------------------------------------------ generic GEMM
// act: 0 -> C0 f32 (+bias) ; 1 -> C1 bf16 relu(+bias)   (phi_x, dec)
template<int MF>
__launch_bounds__(256)
__global__ void k_mm(const u16* __restrict__ A, int lda,
                     const u16* __restrict__ BT, int ldbt, int K,
                     float* __restrict__ C0, int ldc0,
                     u16* __restrict__ C1, int ldc1,
                     const float* __restrict__ bias, int act) {
    constexpr int TILE = MF * 32;
    __shared__ alignas(16) char smem[TILE * 64 * 4];

    const int lane = threadIdx.x & 63;
    const int w = threadIdx.x >> 6;
    const int row0 = blockIdx.y * TILE;
    const int col0 = blockIdx.x * TILE;
    const int wr = (w >> 1) * (TILE / 2);
    const int wc = (w & 1) * (TILE / 2);

    f32x4 acc[MF][MF];
#pragma unroll
    for (int i = 0; i < MF; ++i)
#pragma unroll
        for (int j = 0; j < MF; ++j)
            acc[i][j] = f32x4{0.f, 0.f, 0.f, 0.f};

    mm_core<MF>(A, lda, BT, ldbt, K, row0, col0, acc, smem);

    const int ci = lane & 15;
    const int ri = (lane >> 4) * 4;
#pragma unroll
    for (int mf = 0; mf < MF; ++mf) {
#pragma unroll
        for (int nf = 0; nf < MF; ++nf) {
            int row = row0 + wr + mf * 16 + ri;
            int col = col0 + wc + nf * 16 + ci;
            if (C1) {
                float bv = bias ? bias[col] : 0.f;
#pragma unroll
                for (int i = 0; i < 4; ++i) {
                    float v = acc[mf][nf][i] + bv;
                    if (act == 1) v = fmaxf(v, 0.f);
                    C1[(size_t)(row + i) * ldc1 + col] = f2bf(v);
                }
            } else {
                float bv = bias ? bias[col] : 0.f;
#pragma unroll
                for (int i = 0; i < 4; ++i)
                    C0[(size_t)(row + i) * ldc0 + col] = acc[mf][nf][i] + bv;
            }
        }
    }
}

// ------------------------------------ rect GEMM (32x64 tiles), act 1 or act 4
// act 1: C1 = relu(A@B + bias) bf16. act 4 (mu|std interleaved j*2+s):
//   C0 = out_mu f32, C1 = zbuf bf16; optional du/zdOut.
__launch_bounds__(256)
__global__ void k_mm32(const u16* __restrict__ A, int lda,
                       const u16* __restrict__ BT, int ldbt, int K,
                       float* __restrict__ C0,
                       u16* __restrict__ C1, int ldc1,
                       const float* __restrict__ bias, int act,
                       const float* __restrict__ eps,
                       const float* __restrict__ du, u16* __restrict__ zdOut) {
    __shared__ alignas(16) char smem[12288];
    const int tid = threadIdx.x;
    const int lane = tid & 63;
    const int w = tid >> 6;
    const int row0 = blockIdx.y * 32;
    const int col0 = blockIdx.x * 64;

    f32x4 acc[2];
    acc[0] = f32x4{0.f, 0.f, 0.f, 0.f};
    acc[1] = f32x4{0.f, 0.f, 0.f, 0.f};
    mm_core32(A, lda, BT, ldbt, K, row0, col0, acc, smem);

    if (act == 1) {
        epi32_bf16relu(acc, C1, ldc1, row0, col0, bias);
        return;
    }
    // act 4
    const int wr = (w >> 1) * 16, wc = (w & 1) * 32;
    const int ci = lane & 15, ri = (lane >> 4) * 4;
    float (*epi)[68] = (float(*)[68])smem;
#pragma unroll
    for (int nf = 0; nf < 2; ++nf)
#pragma unroll
        for (int i = 0; i < 4; ++i)
            epi[wr + ri + i][wc + nf * 16 + ci] = acc[nf][i];
    __syncthreads();
#pragma unroll
    for (int k = 0; k < 4; ++k) {
        int p = tid + k * 256;                 // 1024 = 32 rows x 32 jl
        int row = p >> 5, jl = p & 31;
        float mu = epi[row][jl * 2];
        float sp = epi[row][jl * 2 + 1];
        float sd = (sp > 20.f) ? sp : log1pf(expf(sp));
        int idx = (row0 + row) * ZZ + (col0 >> 1) + jl;
        C0[idx] = mu;
        u16 z16 = f2bf(eps[idx] * sd + mu);
        C1[idx] = z16;
        if (zdOut)
            zdOut[idx] = (du[idx] < 0.5f) ? f2bf(2.f * bf2f(z16)) : (u16)0;
    }
}

// ------------ dual GEMM: z=0 enc rect 32x64 (bf16 relu), z=1 prior_mu 64^2 f32
__launch_bounds__(256)
__global__ void k_dual32(const u16* __restrict__ A0, int lda0, const u16* __restrict__ BT0,
                         int ldbt0, int K0, u16* __restrict__ Cb0, int ldcb0,
                         const u16* __restrict__ A1, int lda1, const u16* __restrict__ BT1,
                         int ldbt1, int K1, float* __restrict__ Cf1, int ldcf1,
                         const float* __restrict__ bias1) {
    __shared__ alignas(16) char smem[16384];
    if (blockIdx.z == 0) {
        const int row0 = blockIdx.y * 32;
        const int col0 = blockIdx.x * 64;
        f32x4 acc[2];
        acc[0] = f32x4{0.f, 0.f, 0.f, 0.f};
        acc[1] = f32x4{0.f, 0.f, 0.f, 0.f};
        mm_core32(A0, lda0, BT0, ldbt0, K0, row0, col0, acc, smem);
        epi32_bf16relu(acc, Cb0, ldcb0, row0, col0, nullptr);
    } else {
        if (blockIdx.x >= 2 || blockIdx.y >= 64) return;
        const int row0 = blockIdx.y * 64;
        const int col0 = blockIdx.x * 64;
        f32x4 acc[2][2]; zacc2(acc);
        mm_core<2>(A1, lda1, BT1, ldbt1, K1, row0, col0, acc, smem);
        epi_f32b(acc, Cf1, ldcf1, row0, col0, bias1);
    }
}

// ------------------- hybrid: spmm blocks (NN/4) + 64^2 GEMM blocks (bf16 relu)
__launch_bounds__(256)
__global__ void k_sp_mm(const u16* __restrict__ Y, const int* __restrict__ row_start,
                        const int2* __restrict__ cv,
                        const float* __restrict__ dinv, u16* __restrict__ spOut, int spLdo,
                        int doSp,
                        const u16* __restrict__ A, int lda, const u16* __restrict__ BT,
                        int ldbt, int K, u16* __restrict__ Cb, int ldcb,
                        const float* __restrict__ bias, int gx) {
    __shared__ alignas(16) char smem[16384];
    int bid = blockIdx.x;
    if (bid < NN / 4) {
        if (!doSp) return;
        int w = threadIdx.x >> 6;
        sp_row_wave(Y, row_start, cv, dinv, spOut, spLdo, bid * 4 + w);
        return;
    }
    int b2 = bid - NN / 4;
    const int row0 = (b2 / gx) * 64;
    const int col0 = (b2 % gx) * 64;
    f32x4 acc[2][2]; zacc2(acc);
    mm_core<2>(A, lda, BT, ldbt, K, row0, col0, acc, smem);
    epi_bf16relu(acc, Cb, ldcb, row0, col0, bias);
}

// --------------------------------------------- gates GEMM + fused LSTM update
// BgT col-interleaved gate layout: row cp = j*4+g (N'=1024), K=768.
// Rect tile 128x64, grid (16,32) = 512 blocks.
__launch_bounds__(256)
__global__ void k_gates(const u16* __restrict__ XIN, const u16* __restrict__ BgT,
                        float* __restrict__ h, float* __restrict__ c,
                        u16* __restrict__ hbf, float* __restrict__ hOut,
                        int skipSH) {
    __shared__ alignas(16) char smem[34816];
    u16* As = (u16*)smem;                 // 128x64 = 16KB
    u16* Bs = As + 128 * 64;              // 64x64 = 8KB
    const int tid = threadIdx.x;
    const int lane = tid & 63;
    const int w = tid >> 6;
    const int row0 = blockIdx.y * 128;
    const int col0 = blockIdx.x * 64;
    const int wrB = (w >> 1) * 64;
    const int wc = (w & 1) * 32;

    f32x4 acc[4][2];
#pragma unroll
    for (int i = 0; i < 4; ++i)
#pragma unroll
        for (int j = 0; j < 2; ++j) acc[i][j] = f32x4{0.f, 0.f, 0.f, 0.f};

    int aRow[4], aCol[4];
#pragma unroll
    for (int i = 0; i < 4; ++i) {
        int G = (w * 4 + i) * 64 + lane;
        int r = G >> 3;
        aRow[i] = r;
        aCol[i] = ((G & 7) ^ (r & 7)) << 3;
    }
    int bRow[2], bCol[2];
#pragma unroll
    for (int i = 0; i < 2; ++i) {
        int G = (w * 2 + i) * 64 + lane;
        int r = G >> 3;
        bRow[i] = r;
        bCol[i] = ((G & 7) ^ (r & 7)) << 3;
    }

    const int nIter = skipSH ? 8 : 12;
    for (int it = 0; it < nIter; ++it) {
        int k0 = it * 64 + ((skipSH && it >= 4) ? 256 : 0);
#pragma unroll
        for (int i = 0; i < 4; ++i) {
            const u16* sa = XIN + (size_t)(row0 + aRow[i]) * 768 + k0 + aCol[i];
            __builtin_amdgcn_global_load_lds(
                (const __attribute__((address_space(1))) void*)sa,
                (__attribute__((address_space(3))) void*)(As + (w * 4 + i) * 512), 16, 0, 0);
        }
#pragma unroll
        for (int i = 0; i < 2; ++i) {
            const u16* sb = BgT + (size_t)(col0 + bRow[i]) * 768 + k0 + bCol[i];
            __builtin_amdgcn_global_load_lds(
                (const __attribute__((address_space(1))) void*)sb,
                (__attribute__((address_space(3))) void*)(Bs + (w * 2 + i) * 512), 16, 0, 0);
        }
        __syncthreads();
#pragma unroll
        for (int kk = 0; kk < 2; ++kk) {
            short8 a[4], b[2];
#pragma unroll
            for (int mf = 0; mf < 4; ++mf) {
                int r = wrB + mf * 16 + (lane & 15);
                int off = (r * 128 + kk * 64 + (lane >> 4) * 16) ^ ((r & 7) << 4);
                a[mf] = *(const short8*)((const char*)As + off);
            }
#pragma unroll
            for (int nf = 0; nf < 2; ++nf) {
                int r = wc + nf * 16 + (lane & 15);
                int off = (r * 128 + kk * 64 + (lane >> 4) * 16) ^ ((r & 7) << 4);
                b[nf] = *(const short8*)((const char*)Bs + off);
            }
#pragma unroll
            for (int mf = 0; mf < 4; ++mf)
#pragma unroll
                for (int nf = 0; nf < 2; ++nf)
                    acc[mf][nf] = __builtin_amdgcn_mfma_f32_16x16x32_bf16(
                        a[mf], b[nf], acc[mf][nf], 0, 0, 0);
        }
        __syncthreads();
    }

    const int ci = lane & 15;
    const int ri = (lane >> 4) * 4;
    float (*epi)[68] = (float(*)[68])smem;
#pragma unroll
    for (int mf = 0; mf < 4; ++mf)
#pragma unroll
        for (int nf = 0; nf < 2; ++nf)
#pragma unroll
            for (int i = 0; i < 4; ++i)
                epi[wrB + mf * 16 + ri + i][wc + nf * 16 + ci] = acc[mf][nf][i];
    __syncthreads();
#pragma unroll
    for (int k = 0; k < 8; ++k) {
        int p = tid + k * 256;
        int row = p >> 4, jl = p & 15;
        float4 g4 = *(const float4*)&epi[row][jl * 4];
        float gi = 1.f / (1.f + expf(-g4.x));
        float gf = 1.f / (1.f + expf(-g4.y));
        float go = 1.f / (1.f + expf(-g4.z));
        float ct = tanhf(g4.w);
        int idx = (row0 + row) * H_ + (col0 >> 2) + jl;
        float ho = h[idx], co = c[idx];
        float cn = gf * ho + gi * ct;     // faithful: F*h_old
        float hn = go * tanhf(co);        // faithful: uses old c
        h[idx] = hn;
        c[idx] = cn;
        hbf[idx] = f2bf(hn);
        if (hOut) hOut[idx] = hn;
    }
}

// --------------- all weight prep + x cvt + degcnt zero + pm0 + h/c/h_bf zero
// segments: phi_x_wT 16384 | phi_z_wT 32768 | enc_wT 131072 | prior_wT 65536 |
//           prior_mu_wT 32768 | mulvT' 65536 | BgT 786432 | xcvt 393216 |
//           degz 6144 | pm0 128 | hcz 655360   (total 2,185,344)
__global__ void k_prep(const float* __restrict__ phi_x_w, const float* __restrict__ phi_z_w,
                       const float* __restrict__ enc_w, const float* __restrict__ prior_w,
                       const float* __restrict__ prior_mu_w,
                       const float* __restrict__ enc_mu_w, const float* __restrict__ enc_lv_w,
                       const float* __restrict__ gru_wx, const float* __restrict__ gru_wh,
                       u16* __restrict__ phi_x_wT, u16* __restrict__ phi_z_wT,
                       u16* __restrict__ enc_wT, u16* __restrict__ prior_wT,
                       u16* __restrict__ prior_mu_wT, u16* __restrict__ mulvT,
                       u16* __restrict__ BgT,
                       const float* __restrict__ x, u16* __restrict__ x_bf,
                       int* __restrict__ degcnt,
                       const float* __restrict__ prior_b,
                       const float* __restrict__ prior_mu_b,
                       float* __restrict__ pm0,
                       float4* __restrict__ hcz) {
    int idx = blockIdx.x * 256 + threadIdx.x;
    if (idx < 16384) {                       // phi_x: [64][256] -> [256][64]
        int j = idx >> 6, k = idx & 63;
        phi_x_wT[idx] = f2bf(phi_x_w[k * 256 + j]);
        return;
    }
    idx -= 16384;
    if (idx < 32768) {                       // phi_z: [128][256] -> [256][128]
        int j = idx >> 7, k = idx & 127;
        phi_z_wT[idx] = f2bf(phi_z_w[k * 256 + j]);
        return;
    }
    idx -= 32768;
    if (idx < 131072) {                      // enc: [512][256] -> [256][512]
        int j = idx >> 9, k = idx & 511;
        enc_wT[idx] = f2bf(enc_w[k * 256 + j]);
        return;
    }
    idx -= 131072;
    if (idx < 65536) {                       // prior: [256][256] -> [256][256]
        int j = idx >> 8, k = idx & 255;
        prior_wT[idx] = f2bf(prior_w[k * 256 + j]);
        return;
    }
    idx -= 65536;
    if (idx < 32768) {                       // prior_mu: [256][128] -> [128][256]
        int j = idx >> 8, k = idx & 255;
        prior_mu_wT[idx] = f2bf(prior_mu_w[k * 128 + j]);
        return;
    }
    idx -= 32768;
    if (idx < 65536) {                       // mulv': col' = j*2+s, rows k=256
        int cp = idx >> 8, k = idx & 255;
        int j = cp >> 1, s = cp & 1;
        float v = s ? enc_lv_w[k * 128 + j] : enc_mu_w[k * 128 + j];
        mulvT[idx] = f2bf(v);
        return;
    }
    idx -= 65536;
    if (idx < 786432) {                      // gates interleaved: row cp=j*4+g, K=768
        int cp = idx / 768, k = idx % 768;
        int g = cp & 3, j = cp >> 2;
        float v;
        if (k < 256)      v = gru_wx[((size_t)g * 512 + k) * 256 + j];
        else if (k < 512) v = gru_wh[((size_t)g * 256 + (k - 256)) * 256 + j];
        else              v = gru_wx[((size_t)g * 512 + (k - 256)) * 256 + j];
        BgT[idx] = f2bf(v);
        return;
    }
    idx -= 786432;
    if (idx < 393216) {                      // x f32 -> bf16
        float4 v = ((const float4*)x)[idx];
        ((ushort4*)x_bf)[idx] = make_ushort4(f2bf(v.x), f2bf(v.y), f2bf(v.z), f2bf(v.w));
        return;
    }
    idx -= 393216;
    if (idx < 6144) {                        // degcnt zero
        ((int4*)degcnt)[idx] = make_int4(0, 0, 0, 0);
        return;
    }
    idx -= 6144;
    if (idx < 128) {                         // pm0: t=0 prior_mu row (h=0)
        float acc = prior_mu_b[idx];
        for (int k = 0; k < 256; ++k) {
            float pt = bf2f(f2bf(fmaxf(prior_b[k], 0.f)));
            acc += pt * bf2f(f2bf(prior_mu_w[k * 128 + idx]));
        }
        pm0[idx] = acc;
        return;
    }
    idx -= 128;
    if (idx < 655360)                        // h|c|h_bf zero (10MB)
        hcz[idx] = make_float4(0.f, 0.f, 0.f, 0.f);
}

// ============================================================================
extern "C" void kernel_launch(void* const* d_in, const int* in_sizes, int n_in,
                              void* d_out_v, int out_size, void* d_ws, size_t ws_size,
                              hipStream_t stream) {
    (void)in_sizes; (void)n_in; (void)out_size;
    const float* x          = (const float*)d_in[0];
    const int*   edges      = (const int*)d_in[1];
    const float* eps        = (const float*)d_in[2];
    const float* drop_u     = (const float*)d_in[3];
    const float* phi_x_w    = (const float*)d_in[4];
    const float* phi_x_b    = (const float*)d_in[5];
    const float* phi_z_w    = (const float*)d_in[6];
    const float* phi_z_b    = (const float*)d_in[7];
    const float* enc_w      = (const float*)d_in[8];
    const float* enc_mu_w   = (const float*)d_in[9];
    const float* enc_lv_w   = (const float*)d_in[10];
    const float* prior_w    = (const float*)d_in[11];
    const float* prior_b    = (const float*)d_in[12];
    const float* prior_mu_w = (const float*)d_in[13];
    const float* prior_mu_b = (const float*)d_in[14];
    const float* gru_wx     = (const float*)d_in[17];
    const float* gru_wh     = (const float*)d_in[18];
    float* out = (float*)d_out_v;

    char* base = (char*)d_ws;
    size_t cur = 0;
    auto carve = [&](size_t bytes) -> void* {
        void* p = base + cur;
        cur += (bytes + 255) & ~(size_t)255;
        return p;
    };
    // h, c, h_bf contiguous -> zeroed in k_prep
    float* h         = (float*)carve((size_t)NN * H_ * 4);
    float* c         = (float*)carve((size_t)NN * H_ * 4);
    u16* h_bf        = (u16*)carve((size_t)NN * H_ * 2);
    float* dinv      = (float*)carve((size_t)T_ * NN * 4);
    int*   degcnt    = (int*)carve((size_t)T_ * NN * 4);
    int*   row_start = (int*)carve((size_t)T_ * (NN + 1) * 4);
    int*   cursor    = (int*)carve((size_t)T_ * NN * 4);
    int2*  cv        = (int2*)carve((size_t)T_ * EE * 8);
    u16* x_bf        = (u16*)carve((size_t)T_ * NN * XD_ * 2);
    u16* phi6        = (u16*)carve((size_t)T_ * NN * H_ * 2);
    u16* phiz        = (u16*)carve((size_t)NN * H_ * 2);
    u16* enc_t       = (u16*)carve((size_t)NN * H_ * 2);
    u16* SEb         = (u16*)carve((size_t)NN * H_ * 2);
    u16* prior_t     = (u16*)carve((size_t)NN * H_ * 2);
    u16* XIN6        = (u16*)carve((size_t)T_ * NN * 768 * 2);
    u16* zbuf        = (u16*)carve((size_t)NN * ZZ * 2);
    u16* zd          = (u16*)carve((size_t)NN * ZZ * 2);
    u16* phi_x_wT    = (u16*)carve((size_t)XD_ * H_ * 2);
    u16* phi_z_wT    = (u16*)carve((size_t)ZZ * H_ * 2);
    u16* enc_wT      = (u16*)carve((size_t)512 * H_ * 2);
    u16* prior_wT    = (u16*)carve((size_t)H_ * H_ * 2);
    u16* prior_mu_wT = (u16*)carve((size_t)ZZ * H_ * 2);
    u16* mulvT       = (u16*)carve((size_t)H_ * H_ * 2);
    u16* BgT         = (u16*)carve((size_t)1024 * 768 * 2);
    float* pm0       = (float*)carve(128 * 4);
    if (cur > ws_size) return;

    const size_t NZ = (size_t)NN * ZZ;
    const size_t HOFF = (size_t)2 * T_ * NZ;
    const size_t DECOFF = HOFF + (size_t)NN * H_;

    // ---- prefix: prep (+state zero) + CSR build (+pm0 broadcast) + phi_x + SX
    k_prep<<<(2185344 + 255) / 256, 256, 0, stream>>>(
        phi_x_w, phi_z_w, enc_w, prior_w, prior_mu_w, enc_mu_w, enc_lv_w,
        gru_wx, gru_wh,
        phi_x_wT, phi_z_wT, enc_wT, prior_wT, prior_mu_wT, mulvT, BgT,
        x, x_bf, degcnt, prior_b, prior_mu_b, pm0, (float4*)h);
    k_deg<<<dim3(EE / 256, T_), 256, 0, stream>>>(edges, degcnt);
    k_scan_dinv<<<T_, 1024, 0, stream>>>(degcnt, row_start, cursor, dinv);
    k_scatter<<<(T_ * EE + NN * ZZ / 4 + 255) / 256, 256, 0, stream>>>(
        edges, cursor, dinv, cv, pm0, out + (size_t)T_ * NZ);
    k_mm<2><<<dim3(4, (T_ * NN) / 64), 256, 0, stream>>>(x_bf, XD_, phi_x_wT, XD_, XD_,
        nullptr, 0, phi6, H_, phi_x_b, 1);
    k_spmm<<<dim3(NN / 4, T_), 256, 0, stream>>>(phi6, row_start, cv, dinv,
        XIN6, 768, (long long)NN * H_, (long long)NN * 768);

    for (int t = 0; t < T_; ++t) {
        const int* rs_t = row_start + (size_t)t * (NN + 1);
        const int2* cv_t = cv + (size_t)t * EE;
        const float* dv_t = dinv + (size_t)t * NN;
        u16* xin_t = XIN6 + (size_t)t * NN * 768;
        int last = (t == T_ - 1);

        // ---- P1: SH = S@h -> XIN[:,256:512]  ||  prior_t GEMM  (skip at t=0)
        if (t > 0)
            k_sp_mm<<<NN / 4 + 256, 256, 0, stream>>>(h_bf, rs_t, cv_t, dv_t,
                xin_t + 256, 768, 1,
                h_bf, H_, prior_wT, H_, H_, prior_t, H_, prior_b, 4);
        // ---- P2: enc_t = relu([SX|SH] @ enc_w) (rect)  ||  prior_mu -> out (t>0)
        k_dual32<<<dim3(4, 128, (t == 0) ? 1 : 2), 256, 0, stream>>>(
            xin_t, 768, enc_wT, 512, (t == 0) ? 256 : 512, enc_t, H_,
            prior_t, H_, prior_mu_wT, H_, H_,
            out + (size_t)(T_ + t) * NZ, ZZ, prior_mu_b);
        // ---- P3: SE = S@enc_t
        k_spmm<<<dim3(NN / 4, 1), 256, 0, stream>>>(enc_t, rs_t, cv_t, dv_t,
                                                    SEb, H_, 0, 0);
        // ---- P4: mulv rect GEMM + mu out + z (+zdrop at last)
        k_mm32<<<dim3(4, 128), 256, 0, stream>>>(SEb, H_, mulvT, H_, H_,
            out + (size_t)t * NZ, zbuf, ZZ, nullptr, 4,
            eps + (size_t)t * NZ,
            last ? drop_u + (size_t)t * NZ : nullptr, last ? zd : nullptr);
        // ---- P5: phi_z = relu(z @ phi_z_w + b) (rect)
        k_mm32<<<dim3(4, 128), 256, 0, stream>>>(zbuf, ZZ, phi_z_wT, ZZ, ZZ,
            nullptr, phiz, H_, phi_z_b, 1, nullptr, nullptr, nullptr);
        // ---- P6: SZ = S@phi_z -> XIN[:,512:768]
        k_spmm<<<dim3(NN / 4, 1), 256, 0, stream>>>(phiz, rs_t, cv_t, dv_t,
                                                    xin_t + 512, 768, 0, 0);
        // ---- P7: gates + fused LSTM (writes final h f32 at t=T-1)
        k_gates<<<dim3(16, 32), 256, 0, stream>>>(xin_t, BgT, h, c, h_bf,
            last ? out + HOFF : nullptr, t == 0);
    }

    // ---- dec = z_drop @ z_drop.T (B^T = zd itself)
    k_mm<4><<<dim3(32, 32), 256, 0, stream>>>(zd, ZZ, zd, ZZ, ZZ,
        out + DECOFF, NN, nullptr, 0, nullptr, 0);
}

// Round 14
// 536.352 us; speedup vs baseline: 1.0510x; 1.0510x over previous
//
#include <hip/hip_runtime.h>
#include <math.h>

#define T_  6
#define NN  4096
#define XD_ 64
#define H_  256
#define ZZ  128
#define EE  131072

typedef unsigned short u16;
typedef __attribute__((ext_vector_type(8))) short short8;
typedef __attribute__((ext_vector_type(8))) unsigned short u16x8;
typedef __attribute__((ext_vector_type(4))) float f32x4;

__device__ __forceinline__ float bf2f(u16 u) { return __uint_as_float(((unsigned)u) << 16); }
__device__ __forceinline__ u16 f2bf(float f) {
    unsigned x = __float_as_uint(f);
    return (u16)((x + 0x7FFFu + ((x >> 16) & 1u)) >> 16);   // RTNE
}

// ---------------------------------------------------- degree hist (batched t)
__global__ void k_deg(const int* __restrict__ edges, int* __restrict__ degcnt) {
    int t = blockIdx.y;
    int e = blockIdx.x * 256 + threadIdx.x;
    const int* rows = edges + (size_t)t * 2 * EE;
    atomicAdd(&degcnt[t * NN + rows[e]], 1);
}

// ---------------------------------- scan (CSR offsets) + dinv; one block per t
__global__ void k_scan_dinv(const int* __restrict__ degcnt_all,
                            int* __restrict__ row_start_all,
                            int* __restrict__ cursor_all,
                            float* __restrict__ dinv_all) {
    __shared__ int sbuf[1024];
    int tt = blockIdx.x;
    const int* degcnt = degcnt_all + tt * NN;
    int* row_start = row_start_all + tt * (NN + 1);
    int* cursor = cursor_all + tt * NN;
    float* dinv = dinv_all + tt * NN;
    int t = threadIdx.x;
    int b = t * 4;
    int v0 = degcnt[b + 0], v1 = degcnt[b + 1], v2 = degcnt[b + 2], v3 = degcnt[b + 3];
    dinv[b + 0] = rsqrtf((float)(v0 + 1));   // +1: self loop
    dinv[b + 1] = rsqrtf((float)(v1 + 1));
    dinv[b + 2] = rsqrtf((float)(v2 + 1));
    dinv[b + 3] = rsqrtf((float)(v3 + 1));
    int s = v0 + v1 + v2 + v3;
    sbuf[t] = s;
    __syncthreads();
    for (int off = 1; off < 1024; off <<= 1) {
        int x = sbuf[t];
        int y = (t >= off) ? sbuf[t - off] : 0;
        __syncthreads();
        sbuf[t] = x + y;
        __syncthreads();
    }
    int excl = sbuf[t] - s;
    int r0 = excl, r1 = excl + v0, r2 = r1 + v1, r3 = r2 + v2;
    row_start[b + 0] = r0; cursor[b + 0] = r0;
    row_start[b + 1] = r1; cursor[b + 1] = r1;
    row_start[b + 2] = r2; cursor[b + 2] = r2;
    row_start[b + 3] = r3; cursor[b + 3] = r3;
    if (t == 1023) row_start[NN] = r3 + v3;
}

// --------------------- CSR scatter (1D, batched t) + t=0 prior_mu broadcast
__global__ void k_scatter(const int* __restrict__ edges,
                          int* __restrict__ cursor, const float* __restrict__ dinv,
                          int* __restrict__ col_idx, float* __restrict__ val,
                          const float* __restrict__ pm0, float* __restrict__ out_pm) {
    int idx = blockIdx.x * 256 + threadIdx.x;
    if (idx < T_ * EE) {
        int t = idx >> 17, e = idx & (EE - 1);
        const int* rows = edges + (size_t)t * 2 * EE;
        const int* cols = rows + EE;
        int r = rows[e], cc = cols[e];
        int pos = atomicAdd(&cursor[t * NN + r], 1);
        col_idx[(size_t)t * EE + pos] = cc;
        val[(size_t)t * EE + pos] = dinv[t * NN + r] * dinv[t * NN + cc];
        return;
    }
    idx -= T_ * EE;
    if (idx < NN * ZZ / 4) {                 // broadcast pm0 to out prior_mu t=0
        int j4 = idx & 31;
        ((float4*)out_pm)[idx] = *(const float4*)(pm0 + j4 * 4);
    }
}

// ------------------------------------------------- SpMM row (one wave, bf16)
// 8 edges/iteration: each half-wave handles 4 edges with 4 independent 16B
// gathers in flight. Accumulation order identical to prior versions.
__device__ __forceinline__ void sp_row_wave(const u16* __restrict__ Y,
                                            const int* __restrict__ row_start,
                                            const int* __restrict__ col_idx,
                                            const float* __restrict__ val,
                                            const float* __restrict__ dinv,
                                            u16* __restrict__ outp, int ldo, int r) {
    int lane = threadIdx.x & 63;
    int half = lane >> 5;
    int cg2 = lane & 31;
    int s0 = row_start[r], s1 = row_start[r + 1];
    float a[8] = {0.f, 0.f, 0.f, 0.f, 0.f, 0.f, 0.f, 0.f};
    for (int base = s0; base < s1; base += 64) {
        int n = s1 - base; if (n > 64) n = 64;
        int cl = 0; float vl = 0.f;
        if (base + lane < s1) { cl = col_idx[base + lane]; vl = val[base + lane]; }
        for (int e = 0; e < n; e += 8) {
            int e0 = e + half, e1 = e + 2 + half, e2 = e + 4 + half, e3 = e + 6 + half;
            int cc0 = __shfl(cl, e0);
            float v0 = (e0 < n) ? __shfl(vl, e0) : 0.f;
            int cc1 = __shfl(cl, e1);
            float v1 = (e1 < n) ? __shfl(vl, e1) : 0.f;
            int cc2 = __shfl(cl, e2);
            float v2 = (e2 < n) ? __shfl(vl, e2) : 0.f;
            int cc3 = __shfl(cl, e3);
            float v3 = (e3 < n) ? __shfl(vl, e3) : 0.f;
            u16x8 y0 = *(const u16x8*)(Y + (size_t)cc0 * H_ + cg2 * 8);
            u16x8 y1 = *(const u16x8*)(Y + (size_t)cc1 * H_ + cg2 * 8);
            u16x8 y2 = *(const u16x8*)(Y + (size_t)cc2 * H_ + cg2 * 8);
            u16x8 y3 = *(const u16x8*)(Y + (size_t)cc3 * H_ + cg2 * 8);
#pragma unroll
            for (int j = 0; j < 8; ++j) a[j] += v0 * bf2f(y0[j]);
#pragma unroll
            for (int j = 0; j < 8; ++j) a[j] += v1 * bf2f(y1[j]);
#pragma unroll
            for (int j = 0; j < 8; ++j) a[j] += v2 * bf2f(y2[j]);
#pragma unroll
            for (int j = 0; j < 8; ++j) a[j] += v3 * bf2f(y3[j]);
        }
    }
#pragma unroll
    for (int j = 0; j < 8; ++j) a[j] += __shfl_xor(a[j], 32);
    if (half == 0) {
        float dr = dinv[r], sc = dr * dr;
        u16x8 ys = *(const u16x8*)(Y + (size_t)r * H_ + cg2 * 8);
        u16x8 o;
#pragma unroll
        for (int j = 0; j < 8; ++j) o[j] = f2bf(a[j] + sc * bf2f(ys[j]));
        *(u16x8*)(outp + (size_t)r * ldo + cg2 * 8) = o;
    }
}

// batched-t SpMM: 4 rows per block (1 wave each), grid (NN/4, nt)
__global__ void k_spmm(const u16* __restrict__ Y1,
                       const int* __restrict__ row_start_all, const int* __restrict__ col_idx_all,
                       const float* __restrict__ val_all, const float* __restrict__ dinv_all,
                       u16* __restrict__ out1, int ldo,
                       long long sY, long long sO) {
    int t = blockIdx.y;
    int w = threadIdx.x >> 6;
    sp_row_wave(Y1 + (size_t)t * sY, row_start_all + (size_t)t * (NN + 1),
                col_idx_all + (size_t)t * EE, val_all + (size_t)t * EE,
                dinv_all + (size_t)t * NN, out1 + (size_t)t * sO, ldo,
                blockIdx.x * 4 + w);
}

// ------------------------------------------------------------ MFMA GEMM core
// A row-major bf16, BT = B^T [N][K] bf16; accumulates TILE x TILE at (row0,col0).
// LDS XOR-swizzled (byte ^= (row&7)<<4); staged via global_load_lds with
// pre-swizzled per-lane global source.
template<int MF>
__device__ __forceinline__ void mm_core(const u16* __restrict__ A, int lda,
                                        const u16* __restrict__ BT, int ldbt, int K,
                                        int row0, int col0,
                                        f32x4 acc[MF][MF], char* smem) {
    constexpr int TILE = MF * 32;
    u16* As = (u16*)smem;
    u16* Bs = As + TILE * 64;
    const int lane = threadIdx.x & 63;
    const int w = threadIdx.x >> 6;
    const int wr = (w >> 1) * (TILE / 2);
    const int wc = (w & 1) * (TILE / 2);

    int gRow[MF], gCol[MF];
#pragma unroll
    for (int i = 0; i < MF; ++i) {
        int G = (w * MF + i) * 64 + lane;
        int r = G >> 3;
        gRow[i] = r;
        gCol[i] = ((G & 7) ^ (r & 7)) << 3;
    }

    for (int k0 = 0; k0 < K; k0 += 64) {
#pragma unroll
        for (int i = 0; i < MF; ++i) {
            const u16* sa = A + (size_t)(row0 + gRow[i]) * lda + k0 + gCol[i];
            __builtin_amdgcn_global_load_lds(
                (const __attribute__((address_space(1))) void*)sa,
                (__attribute__((address_space(3))) void*)(As + (w * MF + i) * 512), 16, 0, 0);
            const u16* sb = BT + (size_t)(col0 + gRow[i]) * ldbt + k0 + gCol[i];
            __builtin_amdgcn_global_load_lds(
                (const __attribute__((address_space(1))) void*)sb,
                (__attribute__((address_space(3))) void*)(Bs + (w * MF + i) * 512), 16, 0, 0);
        }
        __syncthreads();
#pragma unroll
        for (int kk = 0; kk < 2; ++kk) {
            short8 a[MF], b[MF];
#pragma unroll
            for (int mf = 0; mf < MF; ++mf) {
                int r = wr + mf * 16 + (lane & 15);
                int off = (r * 128 + kk * 64 + (lane >> 4) * 16) ^ ((r & 7) << 4);
                a[mf] = *(const short8*)((const char*)As + off);
            }
#pragma unroll
            for (int nf = 0; nf < MF; ++nf) {
                int r = wc + nf * 16 + (lane & 15);
                int off = (r * 128 + kk * 64 + (lane >> 4) * 16) ^ ((r & 7) << 4);
                b[nf] = *(const short8*)((const char*)Bs + off);
            }
#pragma unroll
            for (int mf = 0; mf < MF; ++mf)
#pragma unroll
                for (int nf = 0; nf < MF; ++nf)
                    acc[mf][nf] = __builtin_amdgcn_mfma_f32_16x16x32_bf16(
                        a[mf], b[nf], acc[mf][nf], 0, 0, 0);
        }
        __syncthreads();
    }
}

// --------------------------------------------- rect 32x64 tile core (acc[2])
// 4 waves: 2 row-halves (16) x 2 col-halves (32). LDS 12KB.
__device__ __forceinline__ void mm_core32(const u16* __restrict__ A, int lda,
                                          const u16* __restrict__ BT, int ldbt, int K,
                                          int row0, int col0,
                                          f32x4 acc[2], char* smem) {
    u16* As = (u16*)smem;            // 32x64 = 4KB
    u16* Bs = As + 32 * 64;          // 64x64 = 8KB
    const int lane = threadIdx.x & 63;
    const int w = threadIdx.x >> 6;
    const int wr = (w >> 1) * 16;
    const int wc = (w & 1) * 32;

    int aR, aC;
    { int G = w * 64 + lane; int r = G >> 3; aR = r; aC = ((G & 7) ^ (r & 7)) << 3; }
    int bR[2], bC[2];
#pragma unroll
    for (int i = 0; i < 2; ++i) {
        int G = (w * 2 + i) * 64 + lane; int r = G >> 3;
        bR[i] = r; bC[i] = ((G & 7) ^ (r & 7)) << 3;
    }

    for (int k0 = 0; k0 < K; k0 += 64) {
        const u16* sa = A + (size_t)(row0 + aR) * lda + k0 + aC;
        __builtin_amdgcn_global_load_lds(
            (const __attribute__((address_space(1))) void*)sa,
            (__attribute__((address_space(3))) void*)(As + w * 512), 16, 0, 0);
#pragma unroll
        for (int i = 0; i < 2; ++i) {
            const u16* sb = BT + (size_t)(col0 + bR[i]) * ldbt + k0 + bC[i];
            __builtin_amdgcn_global_load_lds(
                (const __attribute__((address_space(1))) void*)sb,
                (__attribute__((address_space(3))) void*)(Bs + (w * 2 + i) * 512), 16, 0, 0);
        }
        __syncthreads();
#pragma unroll
        for (int kk = 0; kk < 2; ++kk) {
            short8 a, b[2];
            {
                int r = wr + (lane & 15);
                int off = (r * 128 + kk * 64 + (lane >> 4) * 16) ^ ((r & 7) << 4);
                a = *(const short8*)((const char*)As + off);
            }
#pragma unroll
            for (int nf = 0; nf < 2; ++nf) {
                int r = wc + nf * 16 + (lane & 15);
                int off = (r * 128 + kk * 64 + (lane >> 4) * 16) ^ ((r & 7) << 4);
                b[nf] = *(const short8*)((const char*)Bs + off);
            }
            acc[0] = __builtin_amdgcn_mfma_f32_16x16x32_bf16(a, b[0], acc[0], 0, 0, 0);
            acc[1] = __builtin_amdgcn_mfma_f32_16x16x32_bf16(a, b[1], acc[1], 0, 0, 0);
        }
        __syncthreads();
    }
}

__device__ __forceinline__ void zacc2(f32x4 acc[2][2]) {
#pragma unroll
    for (int i = 0; i < 2; ++i)
#pragma unroll
        for (int j = 0; j < 2; ++j) acc[i][j] = f32x4{0.f, 0.f, 0.f, 0.f};
}

__device__ __forceinline__ void epi_bf16relu(f32x4 acc[2][2], u16* __restrict__ C,
                                             int ldc, int row0, int col0,
                                             const float* __restrict__ bias) {
    const int lane = threadIdx.x & 63, w = threadIdx.x >> 6;
    const int wr = (w >> 1) * 32, wc = (w & 1) * 32;
    const int ci = lane & 15, ri = (lane >> 4) * 4;
#pragma unroll
    for (int mf = 0; mf < 2; ++mf)
#pragma unroll
        for (int nf = 0; nf < 2; ++nf) {
            int row = row0 + wr + mf * 16 + ri;
            int col = col0 + wc + nf * 16 + ci;
            float bv = bias ? bias[col] : 0.f;
#pragma unroll
            for (int i = 0; i < 4; ++i)
                C[(size_t)(row + i) * ldc + col] = f2bf(fmaxf(acc[mf][nf][i] + bv, 0.f));
        }
}

__device__ __forceinline__ void epi32_bf16relu(f32x4 acc[2], u16* __restrict__ C,
                                               int ldc, int row0, int col0,
                                               const float* __restrict__ bias) {
    const int lane = threadIdx.x & 63, w = threadIdx.x >> 6;
    const int wr = (w >> 1) * 16, wc = (w & 1) * 32;
    const int ci = lane & 15, ri = (lane >> 4) * 4;
#pragma unroll
    for (int nf = 0; nf < 2; ++nf) {
        int row = row0 + wr + ri;
        int col = col0 + wc + nf * 16 + ci;
        float bv = bias ? bias[col] : 0.f;
#pragma unroll
        for (int i = 0; i < 4; ++i)
            C[(size_t)(row + i) * ldc + col] = f2bf(fmaxf(acc[nf][i] + bv, 0.f));
    }
}

__device__ __forceinline__ void epi_f32b(f32x4 acc[2][2], float* __restrict__ C,
                                         int ldc, int row0, int col0,
                                         const float* __restrict__ bias) {
    const int lane = threadIdx.x & 63, w = threadIdx.x >> 6;
    const int wr = (w >> 1) * 32, wc = (w & 1) * 32;
    const int ci = lane & 15, ri = (lane >> 4) * 4;
#pragma unroll
    for (int mf = 0; mf < 2; ++mf)
#pragma unroll
        for (int nf = 0; nf < 2; ++nf) {
            int row = row0 + wr + mf * 16 + ri;
            int col = col0 + wc + nf * 16 + ci;
            float bv = bias[col];
#pragma unroll
            for (int i = 0; i < 4; ++i)
                C[(size_t)(row + i) * ldc + col] = acc[mf][nf][i] + bv;
        }
}

// ------------------------------------------------------------ generic GEMM
// act: 0 -> C0 f32 (+bias) ; 1 -> C1 bf16 relu(+bias)   (phi_x, dec)
template<int MF>
__launch_bounds__(256)
__global__ void k_mm(const u16* __restrict__ A, int lda,
                     const u16* __restrict__ BT, int ldbt, int K,
                     float* __restrict__ C0, int ldc0,
                     u16* __restrict__ C1, int ldc1,
                     const float* __restrict__ bias, int act) {
    constexpr int TILE = MF * 32;
    __shared__ alignas(16) char smem[TILE * 64 * 4];

    const int lane = threadIdx.x & 63;
    const int w = threadIdx.x >> 6;
    const int row0 = blockIdx.y * TILE;
    const int col0 = blockIdx.x * TILE;
    const int wr = (w >> 1) * (TILE / 2);
    const int wc = (w & 1) * (TILE / 2);

    f32x4 acc[MF][MF];
#pragma unroll
    for (int i = 0; i < MF; ++i)
#pragma unroll
        for (int j = 0; j < MF; ++j)
            acc[i][j] = f32x4{0.f, 0.f, 0.f, 0.f};

    mm_core<MF>(A, lda, BT, ldbt, K, row0, col0, acc, smem);

    const int ci = lane & 15;
    const int ri = (lane >> 4) * 4;
#pragma unroll
    for (int mf = 0; mf < MF; ++mf) {
#pragma unroll
        for (int nf = 0; nf < MF; ++nf) {
            int row = row0 + wr + mf * 16 + ri;
            int col = col0 + wc + nf * 16 + ci;
            if (C1) {
                float bv = bias ? bias[col] : 0.f;
#pragma unroll
                for (int i = 0; i < 4; ++i) {
                    float v = acc[mf][nf][i] + bv;
                    if (act == 1) v = fmaxf(v, 0.f);
                    C1[(size_t)(row + i) * ldc1 + col] = f2bf(v);
                }
            } else {
                float bv = bias ? bias[col] : 0.f;
#pragma unroll
                for (int i = 0; i < 4; ++i)
                    C0[(size_t)(row + i) * ldc0 + col] = acc[mf][nf][i] + bv;
            }
        }
    }
}

// ------------------------------------ rect GEMM (32x64 tiles), act 1 or act 4
// act 1: C1 = relu(A@B + bias) bf16. act 4 (mu|std interleaved j*2+s):
//   C0 = out_mu f32, C1 = zbuf bf16; optional du/zdOut.
__launch_bounds__(256)
__global__ void k_mm32(const u16* __restrict__ A, int lda,
                       const u16* __restrict__ BT, int ldbt, int K,
                       float* __restrict__ C0,
                       u16* __restrict__ C1, int ldc1,
                       const float* __restrict__ bias, int act,
                       const float* __restrict__ eps,
                       const float* __restrict__ du, u16* __restrict__ zdOut) {
    __shared__ alignas(16) char smem[12288];
    const int tid = threadIdx.x;
    const int lane = tid & 63;
    const int w = tid >> 6;
    const int row0 = blockIdx.y * 32;
    const int col0 = blockIdx.x * 64;

    f32x4 acc[2];
    acc[0] = f32x4{0.f, 0.f, 0.f, 0.f};
    acc[1] = f32x4{0.f, 0.f, 0.f, 0.f};
    mm_core32(A, lda, BT, ldbt, K, row0, col0, acc, smem);

    if (act == 1) {
        epi32_bf16relu(acc, C1, ldc1, row0, col0, bias);
        return;
    }
    // act 4
    const int wr = (w >> 1) * 16, wc = (w & 1) * 32;
    const int ci = lane & 15, ri = (lane >> 4) * 4;
    float (*epi)[68] = (float(*)[68])smem;
#pragma unroll
    for (int nf = 0; nf < 2; ++nf)
#pragma unroll
        for (int i = 0; i < 4; ++i)
            epi[wr + ri + i][wc + nf * 16 + ci] = acc[nf][i];
    __syncthreads();
#pragma unroll
    for (int k = 0; k < 4; ++k) {
        int p = tid + k * 256;                 // 1024 = 32 rows x 32 jl
        int row = p >> 5, jl = p & 31;
        float mu = epi[row][jl * 2];
        float sp = epi[row][jl * 2 + 1];
        float sd = (sp > 20.f) ? sp : log1pf(expf(sp));
        int idx = (row0 + row) * ZZ + (col0 >> 1) + jl;
        C0[idx] = mu;
        u16 z16 = f2bf(eps[idx] * sd + mu);
        C1[idx] = z16;
        if (zdOut)
            zdOut[idx] = (du[idx] < 0.5f) ? f2bf(2.f * bf2f(z16)) : (u16)0;
    }
}

// ------------ dual GEMM: z=0 enc rect 32x64 (bf16 relu), z=1 prior_mu 64^2 f32
__launch_bounds__(256)
__global__ void k_dual32(const u16* __restrict__ A0, int lda0, const u16* __restrict__ BT0,
                         int ldbt0, int K0, u16* __restrict__ Cb0, int ldcb0,
                         const u16* __restrict__ A1, int lda1, const u16* __restrict__ BT1,
                         int ldbt1, int K1, float* __restrict__ Cf1, int ldcf1,
                         const float* __restrict__ bias1) {
    __shared__ alignas(16) char smem[16384];
    if (blockIdx.z == 0) {
        const int row0 = blockIdx.y * 32;
        const int col0 = blockIdx.x * 64;
        f32x4 acc[2];
        acc[0] = f32x4{0.f, 0.f, 0.f, 0.f};
        acc[1] = f32x4{0.f, 0.f, 0.f, 0.f};
        mm_core32(A0, lda0, BT0, ldbt0, K0, row0, col0, acc, smem);
        epi32_bf16relu(acc, Cb0, ldcb0, row0, col0, nullptr);
    } else {
        if (blockIdx.x >= 2 || blockIdx.y >= 64) return;
        const int row0 = blockIdx.y * 64;
        const int col0 = blockIdx.x * 64;
        f32x4 acc[2][2]; zacc2(acc);
        mm_core<2>(A1, lda1, BT1, ldbt1, K1, row0, col0, acc, smem);
        epi_f32b(acc, Cf1, ldcf1, row0, col0, bias1);
    }
}

// ------------------- hybrid: spmm blocks (NN/4) + 64^2 GEMM blocks (bf16 relu)
__launch_bounds__(256)
__global__ void k_sp_mm(const u16* __restrict__ Y, const int* __restrict__ row_start,
                        const int* __restrict__ col_idx, const float* __restrict__ val,
                        const float* __restrict__ dinv, u16* __restrict__ spOut, int spLdo,
                        int doSp,
                        const u16* __restrict__ A, int lda, const u16* __restrict__ BT,
                        int ldbt, int K, u16* __restrict__ Cb, int ldcb,
                        const float* __restrict__ bias, int gx) {
    __shared__ alignas(16) char smem[16384];
    int bid = blockIdx.x;
    if (bid < NN / 4) {
        if (!doSp) return;
        int w = threadIdx.x >> 6;
        sp_row_wave(Y, row_start, col_idx, val, dinv, spOut, spLdo, bid * 4 + w);
        return;
    }
    int b2 = bid - NN / 4;
    const int row0 = (b2 / gx) * 64;
    const int col0 = (b2 % gx) * 64;
    f32x4 acc[2][2]; zacc2(acc);
    mm_core<2>(A, lda, BT, ldbt, K, row0, col0, acc, smem);
    epi_bf16relu(acc, Cb, ldcb, row0, col0, bias);
}

// --------------------------------------------- gates GEMM + fused LSTM update
// BgT col-interleaved gate layout: row cp = j*4+g (N'=1024), K=768.
// Rect tile 128x64, grid (16,32) = 512 blocks.
__launch_bounds__(256)
__global__ void k_gates(const u16* __restrict__ XIN, const u16* __restrict__ BgT,
                        float* __restrict__ h, float* __restrict__ c,
                        u16* __restrict__ hbf, float* __restrict__ hOut,
                        int skipSH) {
    __shared__ alignas(16) char smem[34816];
    u16* As = (u16*)smem;                 // 128x64 = 16KB
    u16* Bs = As + 128 * 64;              // 64x64 = 8KB
    const int tid = threadIdx.x;
    const int lane = tid & 63;
    const int w = tid >> 6;
    const int row0 = blockIdx.y * 128;
    const int col0 = blockIdx.x * 64;
    const int wrB = (w >> 1) * 64;
    const int wc = (w & 1) * 32;

    f32x4 acc[4][2];
#pragma unroll
    for (int i = 0; i < 4; ++i)
#pragma unroll
        for (int j = 0; j < 2; ++j) acc[i][j] = f32x4{0.f, 0.f, 0.f, 0.f};

    int aRow[4], aCol[4];
#pragma unroll
    for (int i = 0; i < 4; ++i) {
        int G = (w * 4 + i) * 64 + lane;
        int r = G >> 3;
        aRow[i] = r;
        aCol[i] = ((G & 7) ^ (r & 7)) << 3;
    }
    int bRow[2], bCol[2];
#pragma unroll
    for (int i = 0; i < 2; ++i) {
        int G = (w * 2 + i) * 64 + lane;
        int r = G >> 3;
        bRow[i] = r;
        bCol[i] = ((G & 7) ^ (r & 7)) << 3;
    }

    const int nIter = skipSH ? 8 : 12;
    for (int it = 0; it < nIter; ++it) {
        int k0 = it * 64 + ((skipSH && it >= 4) ? 256 : 0);
#pragma unroll
        for (int i = 0; i < 4; ++i) {
            const u16* sa = XIN + (size_t)(row0 + aRow[i]) * 768 + k0 + aCol[i];
            __builtin_amdgcn_global_load_lds(
                (const __attribute__((address_space(1))) void*)sa,
                (__attribute__((address_space(3))) void*)(As + (w * 4 + i) * 512), 16, 0, 0);
        }
#pragma unroll
        for (int i = 0; i < 2; ++i) {
            const u16* sb = BgT + (size_t)(col0 + bRow[i]) * 768 + k0 + bCol[i];
            __builtin_amdgcn_global_load_lds(
                (const __attribute__((address_space(1))) void*)sb,
                (__attribute__((address_space(3))) void*)(Bs + (w * 2 + i) * 512), 16, 0, 0);
        }
        __syncthreads();
#pragma unroll
        for (int kk = 0; kk < 2; ++kk) {
            short8 a[4], b[2];
#pragma unroll
            for (int mf = 0; mf < 4; ++mf) {
                int r = wrB + mf * 16 + (lane & 15);
                int off = (r * 128 + kk * 64 + (lane >> 4) * 16) ^ ((r & 7) << 4);
                a[mf] = *(const short8*)((const char*)As + off);
            }
#pragma unroll
            for (int nf = 0; nf < 2; ++nf) {
                int r = wc + nf * 16 + (lane & 15);
                int off = (r * 128 + kk * 64 + (lane >> 4) * 16) ^ ((r & 7) << 4);
                b[nf] = *(const short8*)((const char*)Bs + off);
            }
#pragma unroll
            for (int mf = 0; mf < 4; ++mf)
#pragma unroll
                for (int nf = 0; nf < 2; ++nf)
                    acc[mf][nf] = __builtin_amdgcn_mfma_f32_16x16x32_bf16(
                        a[mf], b[nf], acc[mf][nf], 0, 0, 0);
        }
        __syncthreads();
    }

    const int ci = lane & 15;
    const int ri = (lane >> 4) * 4;
    float (*epi)[68] = (float(*)[68])smem;
#pragma unroll
    for (int mf = 0; mf < 4; ++mf)
#pragma unroll
        for (int nf = 0; nf < 2; ++nf)
#pragma unroll
            for (int i = 0; i < 4; ++i)
                epi[wrB + mf * 16 + ri + i][wc + nf * 16 + ci] = acc[mf][nf][i];
    __syncthreads();
#pragma unroll
    for (int k = 0; k < 8; ++k) {
        int p = tid + k * 256;
        int row = p >> 4, jl = p & 15;
        float4 g4 = *(const float4*)&epi[row][jl * 4];
        float gi = 1.f / (1.f + expf(-g4.x));
        float gf = 1.f / (1.f + expf(-g4.y));
        float go = 1.f / (1.f + expf(-g4.z));
        float ct = tanhf(g4.w);
        int idx = (row0 + row) * H_ + (col0 >> 2) + jl;
        float ho = h[idx], co = c[idx];
        float cn = gf * ho + gi * ct;     // faithful: F*h_old
        float hn = go * tanhf(co);        // faithful: uses old c
        h[idx] = hn;
        c[idx] = cn;
        hbf[idx] = f2bf(hn);
        if (hOut) hOut[idx] = hn;
    }
}

// --------------- all weight prep + x cvt + degcnt zero + pm0 + h/c/h_bf zero
// segments: phi_x_wT 16384 | phi_z_wT 32768 | enc_wT 131072 | prior_wT 65536 |
//           prior_mu_wT 32768 | mulvT' 65536 | BgT 786432 | xcvt 393216 |
//           degz 6144 | pm0 128 | hcz 655360   (total 2,185,344)
__global__ void k_prep(const float* __restrict__ phi_x_w, const float* __restrict__ phi_z_w,
                       const float* __restrict__ enc_w, const float* __restrict__ prior_w,
                       const float* __restrict__ prior_mu_w,
                       const float* __restrict__ enc_mu_w, const float* __restrict__ enc_lv_w,
                       const float* __restrict__ gru_wx, const float* __restrict__ gru_wh,
                       u16* __restrict__ phi_x_wT, u16* __restrict__ phi_z_wT,
                       u16* __restrict__ enc_wT, u16* __restrict__ prior_wT,
                       u16* __restrict__ prior_mu_wT, u16* __restrict__ mulvT,
                       u16* __restrict__ BgT,
                       const float* __restrict__ x, u16* __restrict__ x_bf,
                       int* __restrict__ degcnt,
                       const float* __restrict__ prior_b,
                       const float* __restrict__ prior_mu_b,
                       float* __restrict__ pm0,
                       float4* __restrict__ hcz) {
    int idx = blockIdx.x * 256 + threadIdx.x;
    if (idx < 16384) {                       // phi_x: [64][256] -> [256][64]
        int j = idx >> 6, k = idx & 63;
        phi_x_wT[idx] = f2bf(phi_x_w[k * 256 + j]);
        return;
    }
    idx -= 16384;
    if (idx < 32768) {                       // phi_z: [128][256] -> [256][128]
        int j = idx >> 7, k = idx & 127;
        phi_z_wT[idx] = f2bf(phi_z_w[k * 256 + j]);
        return;
    }
    idx -= 32768;
    if (idx < 131072) {                      // enc: [512][256] -> [256][512]
        int j = idx >> 9, k = idx & 511;
        enc_wT[idx] = f2bf(enc_w[k * 256 + j]);
        return;
    }
    idx -= 131072;
    if (idx < 65536) {                       // prior: [256][256] -> [256][256]
        int j = idx >> 8, k = idx & 255;
        prior_wT[idx] = f2bf(prior_w[k * 256 + j]);
        return;
    }
    idx -= 65536;
    if (idx < 32768) {                       // prior_mu: [256][128] -> [128][256]
        int j = idx >> 8, k = idx & 255;
        prior_mu_wT[idx] = f2bf(prior_mu_w[k * 128 + j]);
        return;
    }
    idx -= 32768;
    if (idx < 65536) {                       // mulv': col' = j*2+s, rows k=256
        int cp = idx >> 8, k = idx & 255;
        int j = cp >> 1, s = cp & 1;
        float v = s ? enc_lv_w[k * 128 + j] : enc_mu_w[k * 128 + j];
        mulvT[idx] = f2bf(v);
        return;
    }
    idx -= 65536;
    if (idx < 786432) {                      // gates interleaved: row cp=j*4+g, K=768
        int cp = idx / 768, k = idx % 768;
        int g = cp & 3, j = cp >> 2;
        float v;
        if (k < 256)      v = gru_wx[((size_t)g * 512 + k) * 256 + j];
        else if (k < 512) v = gru_wh[((size_t)g * 256 + (k - 256)) * 256 + j];
        else              v = gru_wx[((size_t)g * 512 + (k - 256)) * 256 + j];
        BgT[idx] = f2bf(v);
        return;
    }
    idx -= 786432;
    if (idx < 393216) {                      // x f32 -> bf16
        float4 v = ((const float4*)x)[idx];
        ((ushort4*)x_bf)[idx] = make_ushort4(f2bf(v.x), f2bf(v.y), f2bf(v.z), f2bf(v.w));
        return;
    }
    idx -= 393216;
    if (idx < 6144) {                        // degcnt zero
        ((int4*)degcnt)[idx] = make_int4(0, 0, 0, 0);
        return;
    }
    idx -= 6144;
    if (idx < 128) {                         // pm0: t=0 prior_mu row (h=0)
        float acc = prior_mu_b[idx];
        for (int k = 0; k < 256; ++k) {
            float pt = bf2f(f2bf(fmaxf(prior_b[k], 0.f)));
            acc += pt * bf2f(f2bf(prior_mu_w[k * 128 + idx]));
        }
        pm0[idx] = acc;
        return;
    }
    idx -= 128;
    if (idx < 655360)                        // h|c|h_bf zero (10MB)
        hcz[idx] = make_float4(0.f, 0.f, 0.f, 0.f);
}

// ============================================================================
extern "C" void kernel_launch(void* const* d_in, const int* in_sizes, int n_in,
                              void* d_out_v, int out_size, void* d_ws, size_t ws_size,
                              hipStream_t stream) {
    (void)in_sizes; (void)n_in; (void)out_size;
    const float* x          = (const float*)d_in[0];
    const int*   edges      = (const int*)d_in[1];
    const float* eps        = (const float*)d_in[2];
    const float* drop_u     = (const float*)d_in[3];
    const float* phi_x_w    = (const float*)d_in[4];
    const float* phi_x_b    = (const float*)d_in[5];
    const float* phi_z_w    = (const float*)d_in[6];
    const float* phi_z_b    = (const float*)d_in[7];
    const float* enc_w      = (const float*)d_in[8];
    const float* enc_mu_w   = (const float*)d_in[9];
    const float* enc_lv_w   = (const float*)d_in[10];
    const float* prior_w    = (const float*)d_in[11];
    const float* prior_b    = (const float*)d_in[12];
    const float* prior_mu_w = (const float*)d_in[13];
    const float* prior_mu_b = (const float*)d_in[14];
    const float* gru_wx     = (const float*)d_in[17];
    const float* gru_wh     = (const float*)d_in[18];
    float* out = (float*)d_out_v;

    char* base = (char*)d_ws;
    size_t cur = 0;
    auto carve = [&](size_t bytes) -> void* {
        void* p = base + cur;
        cur += (bytes + 255) & ~(size_t)255;
        return p;
    };
    // h, c, h_bf contiguous -> zeroed in k_prep
    float* h         = (float*)carve((size_t)NN * H_ * 4);
    float* c         = (float*)carve((size_t)NN * H_ * 4);
    u16* h_bf        = (u16*)carve((size_t)NN * H_ * 2);
    float* dinv      = (float*)carve((size_t)T_ * NN * 4);
    int*   degcnt    = (int*)carve((size_t)T_ * NN * 4);
    int*   row_start = (int*)carve((size_t)T_ * (NN + 1) * 4);
    int*   cursor    = (int*)carve((size_t)T_ * NN * 4);
    int*   col_idx   = (int*)carve((size_t)T_ * EE * 4);
    float* val       = (float*)carve((size_t)T_ * EE * 4);
    u16* x_bf        = (u16*)carve((size_t)T_ * NN * XD_ * 2);
    u16* phi6        = (u16*)carve((size_t)T_ * NN * H_ * 2);
    u16* phiz        = (u16*)carve((size_t)NN * H_ * 2);
    u16* enc_t       = (u16*)carve((size_t)NN * H_ * 2);
    u16* SEb         = (u16*)carve((size_t)NN * H_ * 2);
    u16* prior_t     = (u16*)carve((size_t)NN * H_ * 2);
    u16* XIN6        = (u16*)carve((size_t)T_ * NN * 768 * 2);
    u16* zbuf        = (u16*)carve((size_t)NN * ZZ * 2);
    u16* zd          = (u16*)carve((size_t)NN * ZZ * 2);
    u16* phi_x_wT    = (u16*)carve((size_t)XD_ * H_ * 2);
    u16* phi_z_wT    = (u16*)carve((size_t)ZZ * H_ * 2);
    u16* enc_wT      = (u16*)carve((size_t)512 * H_ * 2);
    u16* prior_wT    = (u16*)carve((size_t)H_ * H_ * 2);
    u16* prior_mu_wT = (u16*)carve((size_t)ZZ * H_ * 2);
    u16* mulvT       = (u16*)carve((size_t)H_ * H_ * 2);
    u16* BgT         = (u16*)carve((size_t)1024 * 768 * 2);
    float* pm0       = (float*)carve(128 * 4);
    if (cur > ws_size) return;

    const size_t NZ = (size_t)NN * ZZ;
    const size_t HOFF = (size_t)2 * T_ * NZ;
    const size_t DECOFF = HOFF + (size_t)NN * H_;

    // ---- prefix: prep (+state zero) + CSR build (+pm0 broadcast) + phi_x + SX
    k_prep<<<(2185344 + 255) / 256, 256, 0, stream>>>(
        phi_x_w, phi_z_w, enc_w, prior_w, prior_mu_w, enc_mu_w, enc_lv_w,
        gru_wx, gru_wh,
        phi_x_wT, phi_z_wT, enc_wT, prior_wT, prior_mu_wT, mulvT, BgT,
        x, x_bf, degcnt, prior_b, prior_mu_b, pm0, (float4*)h);
    k_deg<<<dim3(EE / 256, T_), 256, 0, stream>>>(edges, degcnt);
    k_scan_dinv<<<T_, 1024, 0, stream>>>(degcnt, row_start, cursor, dinv);
    k_scatter<<<(T_ * EE + NN * ZZ / 4 + 255) / 256, 256, 0, stream>>>(
        edges, cursor, dinv, col_idx, val, pm0, out + (size_t)T_ * NZ);
    k_mm<2><<<dim3(4, (T_ * NN) / 64), 256, 0, stream>>>(x_bf, XD_, phi_x_wT, XD_, XD_,
        nullptr, 0, phi6, H_, phi_x_b, 1);
    k_spmm<<<dim3(NN / 4, T_), 256, 0, stream>>>(phi6, row_start, col_idx, val, dinv,
        XIN6, 768, (long long)NN * H_, (long long)NN * 768);

    for (int t = 0; t < T_; ++t) {
        const int* rs_t = row_start + (size_t)t * (NN + 1);
        const int* ci_t = col_idx + (size_t)t * EE;
        const float* vv_t = val + (size_t)t * EE;
        const float* dv_t = dinv + (size_t)t * NN;
        u16* xin_t = XIN6 + (size_t)t * NN * 768;
        int last = (t == T_ - 1);

        // ---- P1: SH = S@h -> XIN[:,256:512]  ||  prior_t GEMM  (skip at t=0)
        if (t > 0)
            k_sp_mm<<<NN / 4 + 256, 256, 0, stream>>>(h_bf, rs_t, ci_t, vv_t, dv_t,
                xin_t + 256, 768, 1,
                h_bf, H_, prior_wT, H_, H_, prior_t, H_, prior_b, 4);
        // ---- P2: enc_t = relu([SX|SH] @ enc_w) (rect)  ||  prior_mu -> out (t>0)
        k_dual32<<<dim3(4, 128, (t == 0) ? 1 : 2), 256, 0, stream>>>(
            xin_t, 768, enc_wT, 512, (t == 0) ? 256 : 512, enc_t, H_,
            prior_t, H_, prior_mu_wT, H_, H_,
            out + (size_t)(T_ + t) * NZ, ZZ, prior_mu_b);
        // ---- P3: SE = S@enc_t
        k_spmm<<<dim3(NN / 4, 1), 256, 0, stream>>>(enc_t, rs_t, ci_t, vv_t, dv_t,
                                                    SEb, H_, 0, 0);
        // ---- P4: mulv rect GEMM + mu out + z (+zdrop at last)
        k_mm32<<<dim3(4, 128), 256, 0, stream>>>(SEb, H_, mulvT, H_, H_,
            out + (size_t)t * NZ, zbuf, ZZ, nullptr, 4,
            eps + (size_t)t * NZ,
            last ? drop_u + (size_t)t * NZ : nullptr, last ? zd : nullptr);
        // ---- P5: phi_z = relu(z @ phi_z_w + b) (rect)
        k_mm32<<<dim3(4, 128), 256, 0, stream>>>(zbuf, ZZ, phi_z_wT, ZZ, ZZ,
            nullptr, phiz, H_, phi_z_b, 1, nullptr, nullptr, nullptr);
        // ---- P6: SZ = S@phi_z -> XIN[:,512:768]
        k_spmm<<<dim3(NN / 4, 1), 256, 0, stream>>>(phiz, rs_t, ci_t, vv_t, dv_t,
                                                    xin_t + 512, 768, 0, 0);
        // ---- P7: gates + fused LSTM (writes final h f32 at t=T-1)
        k_gates<<<dim3(16, 32), 256, 0, stream>>>(xin_t, BgT, h, c, h_bf,
            last ? out + HOFF : nullptr, t == 0);
    }

    // ---- dec = z_drop @ z_drop.T (B^T = zd itself)
    k_mm<4><<<dim3(32, 32), 256, 0, stream>>>(zd, ZZ, zd, ZZ, ZZ,
        out + DECOFF, NN, nullptr, 0, nullptr, 0);
}